// Round 17
// baseline (139.875 us; speedup 1.0000x reference)
//
#include <hip/hip_runtime.h>
#include <math.h>

#define B_ 16
#define L_ 256
#define D_ 64

#define CHUNK 16                    // 256 blocks = 1/CU
#define WARM  5                     // R13-proven minimal
#define NCH   (L_ / CHUNK)

#define PITCH 64                    // 16 quads/slot; phys quad = dq ^ swz(slot)
#define NSLOT 63                    // slots 0..61 = h(t-1) rows 0..61; slot 62 = x(t) row 63
#define FBUF  (NSLOT * PITCH)       // 4032 floats
#define LDSZ  (2 * FBUF)            // 8064 floats = 31.5 KB

__device__ __forceinline__ int swz(int s) { return (s + (s >> 1)) & 7; }

// fast tanh via v_exp_f32: overflow/NaN-safe, ~1e-7 rel error (thr 1e-2)
__device__ __forceinline__ float ftanh(float x) {
    float ax = fabsf(x);
    float e  = __builtin_amdgcn_exp2f(-2.8853900818f * ax);   // e^{-2ax}
    float r  = (1.0f - e) * __builtin_amdgcn_rcpf(1.0f + e);
    return copysignf(r, x);
}

// DPP wave shifts with zero boundary fill (bound_ctrl=1).
// Safe ONLY with fully-uniform exec (R11/R15 lesson).
__device__ __forceinline__ float dpp_shr1(float x) {
    int r = __builtin_amdgcn_update_dpp(0, __float_as_int(x), 0x138, 0xF, 0xF, true);
    return __int_as_float(r);
}
__device__ __forceinline__ float dpp_shl1(float x) {
    int r = __builtin_amdgcn_update_dpp(0, __float_as_int(x), 0x130, 0xF, 0xF, true);
    return __int_as_float(r);
}

// ---------------------------------------------------------------------------
// fused_layer v3: rows 0..62 per (b, t-chunk of 16), serial over t.
// Rows 0..31 (x-only): read x(t) windows DIRECTLY from global (6 aligned
// float4/thread, 1-step register prefetch) — no LDS at all (R16 lesson: LDS
// instruction count is the step cost; R7's global slowness was the
// misaligned overlapping windows, fixed by the u0/u1/u2+DPP edge decompose).
// Rows 32..62: read h(t-1) rows 2r-66..2r-64 from LDS slots (slot j = h row
// j; slot 62 = x(t) row 63, staged 2-deep by the r==63 lanes whose compute
// is discarded). All h rows 0..61 written to the other LDS buffer each step.
// WARM=5 warm-up makes chunk starts exact. Row 63 finished by scan63.
__global__ __launch_bounds__(512, 1) void fused_layer(
        const float* __restrict__ X, float* __restrict__ H,
        const float* __restrict__ Wl, const float* __restrict__ bl) {
    __shared__ float lds[LDSZ];

    const int tid    = threadIdx.x;
    const int b      = blockIdx.x >> 4;
    const int ch     = blockIdx.x & (NCH - 1);
    const int T0     = ch * CHUNK;
    const int tw     = (T0 >= WARM) ? (T0 - WARM) : 0;
    const int tend   = T0 + CHUNK;
    const int btbase = b * L_;

    const int r   = tid >> 3;                          // row 0..63
    const int l8  = tid & 7;
    const int q0  = l8 << 1;
    const int c0  = l8 << 3;
    const bool lvl0 = (r < 32);                        // x-sourced rows
    const bool st63 = (r == 63);                       // x-row-63 stagers
    const int  rr   = (r < 62) ? r : 62;               // clamped mid read row

    // mid LDS read offsets: concat row cr = 2*rr-65+ki; slot = cr<0 ? 62 : cr
    int ro0[3], ro1[3];
#pragma unroll
    for (int ki = 0; ki < 3; ++ki) {
        const int cr = 2 * rr - 65 + ki;
        const int s  = (cr < 0) ? 62 : cr;
        const int v  = swz(s);
        ro0[ki] = s * PITCH + ((q0 ^ v) << 2);
        ro1[ki] = s * PITCH + (((q0 + 1) ^ v) << 2);
    }
    // h write offsets (slot r, used when r<=61)
    const int vh  = swz(r);
    const int hw0 = r * PITCH + ((q0 ^ vh) << 2);
    const int hw1 = r * PITCH + (((q0 + 1) ^ vh) << 2);
    // x63 write offsets (slot 62, used when r==63)
    const int v62 = swz(62);
    const int xw0 = 62 * PITCH + ((q0 ^ v62) << 2);
    const int xw1 = 62 * PITCH + (((q0 + 1) ^ v62) << 2);

    const bool le0 = (l8 == 0);
    const bool le7 = (l8 == 7);

    float w[9];
#pragma unroll
    for (int k = 0; k < 9; ++k) w[k] = Wl[k];
    const float bias = bl[0];
    const float4 z4 = make_float4(0.f, 0.f, 0.f, 0.f);

    for (int k = tid; k < LDSZ / 4; k += 512)
        reinterpret_cast<float4*>(lds)[k] = z4;        // h(-1)=0 for chunk 0
    __syncthreads();

    float* cur = lds;
    float* nxt = lds + FBUF;

    // pre-loop: lvl0 loads x(tw) windows; st63 stages x(tw) row 63 + prefetch
    float4 cx[6];
    if (lvl0) {
        const float* xf = X + ((size_t)(btbase + tw) << 12);
#pragma unroll
        for (int ki = 0; ki < 3; ++ki) {
            const int cr = 2 * r - 1 + ki;             // -1..63
            const float* rp = xf + (cr << 6) + c0;
            const bool ok = (cr >= 0);
            cx[ki*2]   = ok ? *reinterpret_cast<const float4*>(rp)     : z4;
            cx[ki*2+1] = ok ? *reinterpret_cast<const float4*>(rp + 4) : z4;
        }
    }
    float4 p63a = z4, p63b = z4;
    if (st63) {
        const float* xf = X + ((size_t)(btbase + tw) << 12) + (63 << 6) + c0;
        *reinterpret_cast<float4*>(cur + xw0) = *reinterpret_cast<const float4*>(xf);
        *reinterpret_cast<float4*>(cur + xw1) = *reinterpret_cast<const float4*>(xf + 4);
        const int t1 = (tw + 1 < L_) ? tw + 1 : L_ - 1;
        const float* xn = X + ((size_t)(btbase + t1) << 12) + (63 << 6) + c0;
        p63a = *reinterpret_cast<const float4*>(xn);
        p63b = *reinterpret_cast<const float4*>(xn + 4);
    }
    __syncthreads();

    for (int t = tw; t < tend; ++t) {
        // prefetch x(t+1) windows (lvl0) and x(t+2) row 63 (st63)
        float4 nx[6];
        if (lvl0) {
            const int tn = (t + 1 < L_) ? t + 1 : L_ - 1;
            const float* xf = X + ((size_t)(btbase + tn) << 12);
#pragma unroll
            for (int ki = 0; ki < 3; ++ki) {
                const int cr = 2 * r - 1 + ki;
                const float* rp = xf + (cr << 6) + c0;
                const bool ok = (cr >= 0);
                nx[ki*2]   = ok ? *reinterpret_cast<const float4*>(rp)     : z4;
                nx[ki*2+1] = ok ? *reinterpret_cast<const float4*>(rp + 4) : z4;
            }
        }
        float4 n63a, n63b;
        if (st63) {
            const int t2 = (t + 2 < L_) ? t + 2 : L_ - 1;
            const float* xn = X + ((size_t)(btbase + t2) << 12) + (63 << 6) + c0;
            n63a = *reinterpret_cast<const float4*>(xn);
            n63b = *reinterpret_cast<const float4*>(xn + 4);
        }

        // ---- compute u0/u1/u2 (g source diverges; FMA+DPP path uniform) ----
        float u0[8], u1[8], u2[8];
#pragma unroll
        for (int k = 0; k < 8; ++k) { u0[k] = 0.f; u1[k] = bias; u2[k] = 0.f; }
#pragma unroll
        for (int ki = 0; ki < 3; ++ki) {
            float g[8];
            if (lvl0) {
                const float4 o0 = cx[ki*2], o1 = cx[ki*2+1];
                g[0]=o0.x; g[1]=o0.y; g[2]=o0.z; g[3]=o0.w;
                g[4]=o1.x; g[5]=o1.y; g[6]=o1.z; g[7]=o1.w;
            } else {
                const float4 o0 = *reinterpret_cast<const float4*>(cur + ro0[ki]);
                const float4 o1 = *reinterpret_cast<const float4*>(cur + ro1[ki]);
                g[0]=o0.x; g[1]=o0.y; g[2]=o0.z; g[3]=o0.w;
                g[4]=o1.x; g[5]=o1.y; g[6]=o1.z; g[7]=o1.w;
            }
            const float wa = w[ki*3], wb = w[ki*3+1], wc = w[ki*3+2];
#pragma unroll
            for (int k = 0; k < 8; ++k) {
                u0[k] = fmaf(wa, g[k], u0[k]);
                u1[k] = fmaf(wb, g[k], u1[k]);
                u2[k] = fmaf(wc, g[k], u2[k]);
            }
        }
        // cross-lane edges — uniform exec
        const float eLr = dpp_shr1(u0[7]);
        const float eRr = dpp_shl1(u2[0]);
        const float eL  = le0 ? 0.f : eLr;
        const float eR  = le7 ? 0.f : eRr;

        float o[8];
        o[0] = ftanh(eL + u1[0] + u2[1]);
#pragma unroll
        for (int k = 1; k < 7; ++k)
            o[k] = ftanh(u0[k-1] + u1[k] + u2[k+1]);
        o[7] = ftanh(u0[6] + u1[7] + eR);

        // ---- predicated stores (after all DPP) ----
        if (r < 63 && t >= T0) {
            float* gd = H + (((size_t)(btbase + t)) << 12) + (r << 6) + c0;
            *reinterpret_cast<float4*>(gd)     = make_float4(o[0],o[1],o[2],o[3]);
            *reinterpret_cast<float4*>(gd + 4) = make_float4(o[4],o[5],o[6],o[7]);
        }
        if (r <= 61) {                                 // h row for next step
            *reinterpret_cast<float4*>(nxt + hw0) = make_float4(o[0],o[1],o[2],o[3]);
            *reinterpret_cast<float4*>(nxt + hw1) = make_float4(o[4],o[5],o[6],o[7]);
        }
        if (st63) {                                    // x(t+1) row 63 -> slot 62
            *reinterpret_cast<float4*>(nxt + xw0) = p63a;
            *reinterpret_cast<float4*>(nxt + xw1) = p63b;
            p63a = n63a; p63b = n63b;
        }
        if (lvl0) {
#pragma unroll
            for (int k = 0; k < 6; ++k) cx[k] = nx[k];
        }
        __syncthreads();
        float* tmp = cur; cur = nxt; nxt = tmp;
    }
}

// ---------------------------------------------------------------------------
// Sequential scan for row 63 (reads rows 61/62 from global, written above).
#define SDEPTH 16
__global__ void scan63(float* __restrict__ dst,
                       const float* __restrict__ src,
                       const float* __restrict__ Wl,
                       const float* __restrict__ bl) {
    const int b = blockIdx.x;
    const int j = threadIdx.x;                         // 0..63, one wave
    float w[9];
#pragma unroll
    for (int k = 0; k < 9; ++k) w[k] = Wl[k];
    const float bias = bl[0];

    const size_t ST = (size_t)D_ * D_;
    const float* s61 = src + (size_t)b * L_ * ST + 61 * 64 + j;
    const float* s62 = src + (size_t)b * L_ * ST + 62 * 64 + j;
    float*       d63 = dst + (size_t)b * L_ * ST + 63 * 64 + j;

    float s = ftanh(bias);                             // t=0: h_{-1}=0
    d63[0] = s;

    float p61[SDEPTH], p62[SDEPTH];
#pragma unroll
    for (int u = 0; u < SDEPTH; ++u) {
        p61[u] = s61[(size_t)u * ST];
        p62[u] = s62[(size_t)u * ST];
    }

    for (int t0 = 1; t0 < 256; t0 += SDEPTH) {
#pragma unroll
        for (int u = 0; u < SDEPTH; ++u) {
            const int t = t0 + u;
            if (t > 255) break;
            const float r61 = p61[u], r62 = p62[u];
            int tp = t + SDEPTH - 1;
            if (tp > 255) tp = 255;
            p61[u] = s61[(size_t)tp * ST];
            p62[u] = s62[(size_t)tp * ST];
            float l1 = dpp_shr1(r61), q1 = dpp_shl1(r61);
            float l2 = dpp_shr1(r62), q2 = dpp_shl1(r62);
            float p = bias;
            p = fmaf(w[0], l1, p); p = fmaf(w[1], r61, p); p = fmaf(w[2], q1, p);
            p = fmaf(w[3], l2, p); p = fmaf(w[4], r62, p); p = fmaf(w[5], q2, p);
            float ls = dpp_shr1(s), rs = dpp_shl1(s);
            float z = fmaf(w[6], ls, fmaf(w[7], s, fmaf(w[8], rs, p)));
            s = ftanh(z);
            d63[(size_t)t * ST] = s;
        }
    }
}

extern "C" void kernel_launch(void* const* d_in, const int* in_sizes, int n_in,
                              void* d_out, int out_size, void* d_ws, size_t ws_size,
                              hipStream_t stream) {
    const float* x    = (const float*)d_in[0];   // (B,L,D,D)
    const float* W    = (const float*)d_in[1];   // (2,1,1,3,3)
    const float* bias = (const float*)d_in[2];   // (2,)
    float* out = (float*)d_out;
    float* h1  = (float*)d_ws;

    for (int l = 0; l < 2; ++l) {
        const float* X  = (l == 0) ? x  : h1;
        float*       H  = (l == 0) ? h1 : out;
        fused_layer<<<B_ * NCH, 512, 0, stream>>>(X, H, W + l * 9, bias + l);
        scan63<<<B_, 64, 0, stream>>>(H, H, W + l * 9, bias + l);
    }
}